// Round 10
// baseline (213.639 us; speedup 1.0000x reference)
//
#include <hip/hip_runtime.h>
#include <math.h>

#define DD 2048
#define EE 64
#define TM 64                 // tokens per block; grid = 256 = 1 block/CU
#define THREADS 512           // 8 waves: 4 token-tiles x 2 expert-halves
#define NKSTEP 64             // 2048/32 MFMA K-steps
#define NCH 4                 // K mega-chunks of 512
#define EROWB 2064            // W-image expert row stride: bank start = (4*r16+8*kg)%32
                              // -> exactly 8 words/bank (floor) on every b128 B-read
#define CHUNKB (512*16*17)    // 139264 B padded chunk image (data = 64*2064 = 132096)

typedef _Float16 f16x8 __attribute__((ext_vector_type(8)));
typedef float    f32x4 __attribute__((ext_vector_type(4)));

// lgkm-only barrier: drains DS ops; global loads (reg dests) stay in flight.
#define BARRIER() { asm volatile("s_waitcnt lgkmcnt(0)" ::: "memory"); \
                    __builtin_amdgcn_s_barrier(); \
                    __builtin_amdgcn_sched_barrier(0); }

// split 8 consecutive f32 (scaled by 32) into f16 hi + f16 lo
__device__ static inline void split8(const float4 a, const float4 b,
                                     f16x8& hi, f16x8& lo) {
    const float S = 32.f;     // keeps lo parts out of f16 subnormal flush range
    const float v[8] = {a.x * S, a.y * S, a.z * S, a.w * S,
                        b.x * S, b.y * S, b.z * S, b.w * S};
#pragma unroll
    for (int i = 0; i < 8; ++i) {
        const _Float16 h = (_Float16)v[i];
        hi[i] = h;
        lo[i] = (_Float16)(v[i] - (float)h);
    }
}

// prologue: W (f32 [E][D]) -> 4 per-chunk LDS images in workspace
__global__ __launch_bounds__(256) void wsplit_kernel(
    const float* __restrict__ W, char* __restrict__ wsp)
{
    const int gid = blockIdx.x * 256 + threadIdx.x;   // 0..16383
    const int e  = gid >> 8;          // expert 0..63
    const int G  = gid & 255;         // global 8-k group
    const int c  = G >> 6;            // mega-chunk 0..3
    const int gk = G & 63;            // group within chunk
    const float4 a = *(const float4*)&W[(size_t)e * DD + G * 8];
    const float4 b = *(const float4*)&W[(size_t)e * DD + G * 8 + 4];
    f16x8 hi, lo;
    split8(a, b, hi, lo);
    char* dst = wsp + (size_t)c * CHUNKB + e * EROWB + gk * 32;
    *(f16x8*)dst        = hi;
    *(f16x8*)(dst + 16) = lo;
}

__global__ __launch_bounds__(THREADS, 2) void router_kernel(
    const float* __restrict__ x, const char* __restrict__ wsp,
    const float* __restrict__ bias_g, float* __restrict__ out, int n_tokens)
{
    __shared__ __attribute__((aligned(16))) char  ldsw[CHUNKB];          // 139264 B
    __shared__ __attribute__((aligned(16))) float logits[TM * (EE + 1)]; // 16640 B

    const int tid   = threadIdx.x;
    const int tBase = blockIdx.x * TM;

    const int wv = tid >> 6, lane = tid & 63;
    const int mt = wv & 3;            // token tile 0..3
    const int eh = wv >> 2;           // expert half 0..1 (tiles 2eh, 2eh+1)
    const int r16 = lane & 15;
    const int kg  = lane >> 4;

    // A-frag source: lane = 8 consecutive k of its token row (global, no LDS)
    const float* xr = x + (size_t)(tBase + mt * 16 + r16) * DD + kg * 8;

    // B-frag LDS bases for the wave's two expert tiles
    const int b0 = (eh * 32 + r16) * EROWB + kg * 32;
    const int b1 = b0 + 16 * EROWB;

    f32x4 acc0 = {0.f, 0.f, 0.f, 0.f};
    f32x4 acc1 = {0.f, 0.f, 0.f, 0.f};

    // 4-deep named x prefetch (compile-time reg indices only)
    float4 xa0, xa1, xb0, xb1, xc0, xc1, xd0, xd1;

#define XLOAD(t_, u, v) { u = *(const float4*)&xr[(t_) * 32]; \
                          v = *(const float4*)&xr[(t_) * 32 + 4]; }

    // stage one 139264-B W-chunk image: linear copy, 17 b128 per thread,
    // loads run one iteration ahead of ds_writes
#define STAGE(c_) { \
    const char* src = wsp + (size_t)(c_) * CHUNKB; \
    int o = tid * 16; \
    float4 ra = *(const float4*)(src + o); \
    _Pragma("unroll") \
    for (int i = 0; i < 16; ++i) { \
        const float4 rb = *(const float4*)(src + o + 8192); \
        *(float4*)(ldsw + o) = ra; \
        ra = rb; o += 8192; \
    } \
    *(float4*)(ldsw + o) = ra; }

#define MFMA16(a_, b_, c_) __builtin_amdgcn_mfma_f32_16x16x32_f16(a_, b_, c_, 0, 0, 0)

    // one K-step: in-reg split, next x load, 4 LDS B-reads, 6 MFMA
#define STEP(t_, u, v, DOLOAD) { \
    f16x8 ah, al; split8(u, v, ah, al); \
    if (DOLOAD) XLOAD((t_) + 4, u, v); \
    const int ko = ((t_) & 15) * 128; \
    const f16x8 bh0 = *(const f16x8*)(ldsw + b0 + ko); \
    const f16x8 bl0 = *(const f16x8*)(ldsw + b0 + ko + 16); \
    const f16x8 bh1 = *(const f16x8*)(ldsw + b1 + ko); \
    const f16x8 bl1 = *(const f16x8*)(ldsw + b1 + ko + 16); \
    acc0 = MFMA16(ah, bh0, acc0); \
    acc0 = MFMA16(al, bh0, acc0); \
    acc0 = MFMA16(ah, bl0, acc0); \
    acc1 = MFMA16(ah, bh1, acc1); \
    acc1 = MFMA16(al, bh1, acc1); \
    acc1 = MFMA16(ah, bl1, acc1); }

#define STEPS16(t0_, DOLOAD12_15) { \
    STEP((t0_) + 0,  xa0, xa1, true); STEP((t0_) + 1,  xb0, xb1, true); \
    STEP((t0_) + 2,  xc0, xc1, true); STEP((t0_) + 3,  xd0, xd1, true); \
    STEP((t0_) + 4,  xa0, xa1, true); STEP((t0_) + 5,  xb0, xb1, true); \
    STEP((t0_) + 6,  xc0, xc1, true); STEP((t0_) + 7,  xd0, xd1, true); \
    STEP((t0_) + 8,  xa0, xa1, true); STEP((t0_) + 9,  xb0, xb1, true); \
    STEP((t0_) + 10, xc0, xc1, true); STEP((t0_) + 11, xd0, xd1, true); \
    STEP((t0_) + 12, xa0, xa1, DOLOAD12_15); STEP((t0_) + 13, xb0, xb1, DOLOAD12_15); \
    STEP((t0_) + 14, xc0, xc1, DOLOAD12_15); STEP((t0_) + 15, xd0, xd1, DOLOAD12_15); }

    // ---- pipeline: 8 barriers total; x prefetch crosses them (lgkm-only) ----
    STAGE(0);
    XLOAD(0, xa0, xa1); XLOAD(1, xb0, xb1);
    XLOAD(2, xc0, xc1); XLOAD(3, xd0, xd1);
    BARRIER();                          // W chunk 0 visible

    for (int c = 0; c < NCH - 1; ++c) {
        STEPS16(c * 16, true);          // max load t = c*16+15+4 <= 55 < 64
        BARRIER();                      // all waves done reading chunk c
        STAGE(c + 1);
        BARRIER();                      // chunk c+1 visible
    }
    STEPS16(48, false);                 // last chunk: steps 60..63 load nothing

    // ---- epilogue: unscale (acc = 1024 * logit), add bias, top-2 ----
    const int col0 = eh * 32 + r16;
    const int col1 = col0 + 16;
    const float bc0 = bias_g[col0];
    const float bc1 = bias_g[col1];
    const float INV = 1.f / 1024.f;
    const int rbase = mt * 16 + kg * 4;
#pragma unroll
    for (int r = 0; r < 4; ++r) {
        logits[(rbase + r) * (EE + 1) + col0] = acc0[r] * INV + bc0;
        logits[(rbase + r) * (EE + 1) + col1] = acc1[r] * INV + bc1;
    }
    __syncthreads();

    if (tid < TM) {
        const float* lrow = &logits[tid * (EE + 1)];
        float v1 = -INFINITY, v2 = -INFINITY;
        int   i1 = 0, i2 = 0;
        for (int e = 0; e < EE; ++e) {
            const float v = lrow[e];
            if (v > v1) { v2 = v1; i2 = i1; v1 = v; i1 = e; }
            else if (v > v2) { v2 = v; i2 = e; }
        }
        const float ed  = expf(v2 - v1);
        const float inv = 1.f / (1.f + ed);
        const int tok = tBase + tid;
        out[tok * 2 + 0] = inv;
        out[tok * 2 + 1] = ed * inv;
        float* oidx = out + (size_t)2 * n_tokens;
        oidx[tok * 2 + 0] = (float)i1;
        oidx[tok * 2 + 1] = (float)i2;
    }
}

extern "C" void kernel_launch(void* const* d_in, const int* in_sizes, int n_in,
                              void* d_out, int out_size, void* d_ws, size_t ws_size,
                              hipStream_t stream) {
    const float* x = (const float*)d_in[0];
    const float* W = (const float*)d_in[1];
    const float* b = (const float*)d_in[2];
    float* out = (float*)d_out;

    const int n_tokens = in_sizes[0] / DD;      // 16384
    const int n_blocks = n_tokens / TM;         // 256 = 1 block/CU

    char* wsp = (char*)d_ws;                    // 4 x 139264 B W-chunk images

    wsplit_kernel<<<(EE * DD / 8) / 256, 256, 0, stream>>>(W, wsp);
    router_kernel<<<n_blocks, THREADS, 0, stream>>>(x, wsp, b, out, n_tokens);
}